// Round 3
// baseline (613.044 us; speedup 1.0000x reference)
//
#include <hip/hip_runtime.h>
#include <math.h>

// ---- problem constants ----
#define TB        128           // threads per block (main kernel)
#define NPOS      131072        // B*H*W positions
#define KCODES    512
#define DIM       64
#define HW        4096          // H*W
#define ROWD      17            // float4 per LDS row (68 dwords: 16B-aligned, stride-1-equivalent banks)
#define LOSS_OFF  8388608ull
#define ENC_OFF   8388609ull
#define PERP_OFF  75497473ull

__device__ __forceinline__ float tree8(float r0, float r1, float r2, float r3,
                                       float r4, float r5, float r6, float r7) {
    // numpy pairwise combine: ((r0+r1)+(r2+r3)) + ((r4+r5)+(r6+r7))
    return __fadd_rn(__fadd_rn(__fadd_rn(r0, r1), __fadd_rn(r2, r3)),
                     __fadd_rn(__fadd_rn(r4, r5), __fadd_rn(r6, r7)));
}

// Prep: ww[k] = sum(w[k]^2) in numpy pairwise order; zero counts + loss accumulator.
extern "C" __global__ __launch_bounds__(512)
void vq_prep(const float* __restrict__ w, float* __restrict__ ww,
             int* __restrict__ counts, float* __restrict__ lossAcc)
{
    const int k = threadIdx.x;                 // 512 threads
    const float* wk = w + k * DIM;
    float r[8];
    #pragma unroll
    for (int i = 0; i < 8; ++i) {
        #pragma unroll
        for (int j = 0; j < 8; ++j) {
            float v = wk[i * 8 + j];
            float pp = __fmul_rn(v, v);
            r[j] = (i == 0) ? pp : __fadd_rn(r[j], pp);
        }
    }
    ww[k] = tree8(r[0], r[1], r[2], r[3], r[4], r[5], r[6], r[7]);
    counts[k] = 0;
    if (k == 0) *lossAcc = 0.0f;
}

// Main kernel, R3 structure: per-lane x (doubled) lives in an LDS row owned by
// that lane (explicit fast "spill"; no barrier needed — self read/write only).
// K-loop blocks 4 codes per pass: one ds_read_b128 (4 dims) feeds 16 FMAs.
// R1/R2 failure: compiler would not keep xd2[64] in VGPRs (VGPR_Count=60),
// re-fetching per k-iter through scratch/L2 -> 310us latency-bound.
extern "C" __global__ __launch_bounds__(TB, 2)
void vq_main(const float* __restrict__ x, const float* __restrict__ w,
             const float* __restrict__ ww, float* __restrict__ out,
             int* __restrict__ counts, float* __restrict__ lossAcc)
{
    __shared__ float4 xls[TB * ROWD];          // 34816 B
    __shared__ int    hcount[KCODES];
    __shared__ float  lred[TB];

    const int tid = threadIdx.x;
    const int n   = blockIdx.x * TB + tid;     // position index (4096 % TB == 0: no b straddle)
    const int b   = n >> 12;                   // n / 4096
    const int hw  = n & 4095;

    #pragma unroll
    for (int i = 0; i < 4; ++i) hcount[tid + i * TB] = 0;

    // ---- prologue: load x (channel stride HW), stash 2x in own LDS row,
    // build A = sum(x^2) replicating numpy pairwise_sum(64):
    // chunk c -> (i = c>>1, j = (c&1)*4+e); each r[j] sees i ascending.
    const float* xp = x + ((size_t)b * DIM) * HW + hw;
    float4* xrow = &xls[tid * ROWD];
    float r[8];
    #pragma unroll
    for (int c = 0; c < 16; ++c) {
        float v[4];
        #pragma unroll
        for (int e = 0; e < 4; ++e) v[e] = xp[(size_t)(4 * c + e) * HW];
        float4 ch;
        ch.x = v[0] + v[0]; ch.y = v[1] + v[1];     // exact doubling
        ch.z = v[2] + v[2]; ch.w = v[3] + v[3];
        xrow[c] = ch;                               // ds_write_b128, own row
        #pragma unroll
        for (int e = 0; e < 4; ++e) {
            const int j = (c & 1) * 4 + e;
            float pp = __fmul_rn(v[e], v[e]);
            if (c < 2) r[j] = pp;
            else       r[j] = __fadd_rn(r[j], pp);
        }
    }
    const float A = tree8(r[0], r[1], r[2], r[3], r[4], r[5], r[6], r[7]);

    // ---- argmin over codes, 4 codes per pass; zero-fill own encodings row.
    float best  = INFINITY;
    int   bestk = 0;
    float* er = out + ENC_OFF + (size_t)n * KCODES;   // odd-float base: dword stores only

    for (int k0 = 0; k0 < KCODES; k0 += 4) {
        float acc[4][8];
        const float* wp = w + (size_t)k0 * DIM;       // wave-uniform -> s_load path
        #pragma unroll
        for (int c = 0; c < 16; ++c) {
            float4 xc4 = xrow[c];                     // ds_read_b128, reused by 4 codes
            float xc[4] = {xc4.x, xc4.y, xc4.z, xc4.w};
            #pragma unroll
            for (int kk = 0; kk < 4; ++kk) {
                const float* wk = wp + kk * DIM + 4 * c;
                #pragma unroll
                for (int e = 0; e < 4; ++e) {
                    const int j = (c & 1) * 4 + e;
                    if (c < 2) acc[kk][j] = __fmul_rn(xc[e], wk[e]);   // == fmaf(a,b,0)
                    else       acc[kk][j] = __fmaf_rn(xc[e], wk[e], acc[kk][j]);
                }
            }
        }
        #pragma unroll
        for (int kk = 0; kk < 4; ++kk) {
            float dot  = tree8(acc[kk][0], acc[kk][1], acc[kk][2], acc[kk][3],
                               acc[kk][4], acc[kk][5], acc[kk][6], acc[kk][7]);
            float t    = __fadd_rn(A, ww[k0 + kk]);   // (||x||^2 + ||w_k||^2), ref order
            float dist = __fadd_rn(t, -dot);          // minus 2*x.w
            if (dist < best) { best = dist; bestk = k0 + kk; }
        }
        er[k0 + 0] = 0.0f; er[k0 + 1] = 0.0f;         // zero-fill drains behind FMAs
        er[k0 + 2] = 0.0f; er[k0 + 3] = 0.0f;
    }

    __syncthreads();   // vmcnt(0) drain of zero stores; hcount init visible

    er[bestk] = 1.0f;                                 // same thread wrote the zero
    atomicAdd(&hcount[bestk], 1);

    // ---- quantized output (transposed back) + SSE partial
    const float4* wrow = reinterpret_cast<const float4*>(w + (size_t)bestk * DIM);
    float* qo = out + ((size_t)b * DIM) * HW + hw;
    float sse = 0.0f;
    #pragma unroll
    for (int c = 0; c < 16; ++c) {
        float4 q  = wrow[c];
        float4 xc = xrow[c];                          // 2x, so 0.5f* is exact
        qo[(size_t)(4 * c + 0) * HW] = q.x;
        qo[(size_t)(4 * c + 1) * HW] = q.y;
        qo[(size_t)(4 * c + 2) * HW] = q.z;
        qo[(size_t)(4 * c + 3) * HW] = q.w;
        float e0 = q.x - 0.5f * xc.x; sse = __fmaf_rn(e0, e0, sse);
        float e1 = q.y - 0.5f * xc.y; sse = __fmaf_rn(e1, e1, sse);
        float e2 = q.z - 0.5f * xc.z; sse = __fmaf_rn(e2, e2, sse);
        float e3 = q.w - 0.5f * xc.w; sse = __fmaf_rn(e3, e3, sse);
    }
    lred[tid] = sse;
    __syncthreads();

    // histogram drain (after barrier: all hcount atomics done)
    #pragma unroll
    for (int i = 0; i < 4; ++i) {
        int c0 = hcount[tid + i * TB];
        if (c0) atomicAdd(&counts[tid + i * TB], c0);
    }

    // block loss reduction
    for (int s = TB / 2; s > 0; s >>= 1) {
        if (tid < s) lred[tid] += lred[tid + s];
        __syncthreads();
    }
    if (tid == 0) atomicAdd(lossAcc, lred[0]);
}

// Finalize: loss scalar + perplexity from histogram.
extern "C" __global__ __launch_bounds__(512)
void vq_finalize(const int* __restrict__ counts, const float* __restrict__ lossAcc,
                 float* __restrict__ out)
{
    __shared__ double sred[KCODES];
    const int t = threadIdx.x;                 // 512 threads
    double p = (double)counts[t] * (1.0 / (double)NPOS);
    sred[t] = -p * log(p + 1e-10);
    __syncthreads();
    for (int s = KCODES / 2; s > 0; s >>= 1) {
        if (t < s) sred[t] += sred[t + s];
        __syncthreads();
    }
    if (t == 0) {
        out[PERP_OFF] = (float)exp(sred[0]);
        out[LOSS_OFF] = 1.25f * (lossAcc[0] / 8388608.0f);
    }
}

extern "C" void kernel_launch(void* const* d_in, const int* in_sizes, int n_in,
                              void* d_out, int out_size, void* d_ws, size_t ws_size,
                              hipStream_t stream)
{
    const float* x = (const float*)d_in[0];    // [32,64,64,64] fp32
    const float* w = (const float*)d_in[1];    // [512,64] fp32
    float* out = (float*)d_out;

    float* ww      = (float*)d_ws;                         // 512 floats
    int*   counts  = (int*)((char*)d_ws + 2048);           // 512 ints
    float* lossAcc = (float*)((char*)d_ws + 4096);         // 1 float

    vq_prep<<<1, 512, 0, stream>>>(w, ww, counts, lossAcc);
    vq_main<<<NPOS / TB, TB, 0, stream>>>(x, w, ww, out, counts, lossAcc);
    vq_finalize<<<1, 512, 0, stream>>>(counts, lossAcc, out);
}

// Round 4
// 550.091 us; speedup vs baseline: 1.1144x; 1.1144x over previous
//
#include <hip/hip_runtime.h>
#include <math.h>

// ---- problem constants ----
#define TB        128           // threads per block (main kernel)
#define NPOS      131072        // B*H*W positions
#define KCODES    512
#define DIM       64
#define HW        4096          // H*W
#define ROWD      17            // float4 per LDS row (68 dwords; 68%32==4 -> same banks as stride-1 b128)
#define LOSS_OFF  8388608ull
#define ENC_OFF   8388609ull
#define PERP_OFF  75497473ull

__device__ __forceinline__ float tree8(float r0, float r1, float r2, float r3,
                                       float r4, float r5, float r6, float r7) {
    // numpy pairwise combine: ((r0+r1)+(r2+r3)) + ((r4+r5)+(r6+r7))
    return __fadd_rn(__fadd_rn(__fadd_rn(r0, r1), __fadd_rn(r2, r3)),
                     __fadd_rn(__fadd_rn(r4, r5), __fadd_rn(r6, r7)));
}

// Prep: ww[k] = sum(w[k]^2) in numpy pairwise order; zero counts + loss accumulator.
extern "C" __global__ __launch_bounds__(512)
void vq_prep(const float* __restrict__ w, float* __restrict__ ww,
             int* __restrict__ counts, float* __restrict__ lossAcc)
{
    const int k = threadIdx.x;                 // 512 threads
    const float* wk = w + k * DIM;
    float r[8];
    #pragma unroll
    for (int i = 0; i < 8; ++i) {
        #pragma unroll
        for (int j = 0; j < 8; ++j) {
            float v = wk[i * 8 + j];
            float pp = __fmul_rn(v, v);
            r[j] = (i == 0) ? pp : __fadd_rn(r[j], pp);
        }
    }
    ww[k] = tree8(r[0], r[1], r[2], r[3], r[4], r[5], r[6], r[7]);
    counts[k] = 0;
    if (k == 0) *lossAcc = 0.0f;
}

// Main kernel. R3 compute structure (x in private LDS rows, 4 codes/pass,
// verified numerics) + R4 store fix: coalesced float4 zero-fill of the
// block's encodings tile. R3's per-thread-row dword fill put lanes 2048B
// apart -> 64 transactions per store, WRITE_SIZE 740MB, store-pipe bound.
// Tile = 65536 dwords at T0 (T0%4==1): dwords d=3+4m are 16B-aligned.
// m=16383's float4 would cross into the next tile (race vs its one-hot) ->
// excluded; edge dwords d=0,1,2,65535 written by threads 0..3 pre-barrier.
extern "C" __global__ __launch_bounds__(TB, 2)
void vq_main(const float* __restrict__ x, const float* __restrict__ w,
             const float* __restrict__ ww, float* __restrict__ out,
             int* __restrict__ counts, float* __restrict__ lossAcc)
{
    __shared__ float4 xls[TB * ROWD];          // 34816 B
    __shared__ int    hcount[KCODES];
    __shared__ float  lred[TB];

    const int tid = threadIdx.x;
    const int n   = blockIdx.x * TB + tid;     // position index (4096 % TB == 0: no b straddle)
    const int b   = n >> 12;                   // n / 4096
    const int hw  = n & 4095;

    #pragma unroll
    for (int i = 0; i < 4; ++i) hcount[tid + i * TB] = 0;

    // ---- prologue: load x (channel stride HW), stash 2x in own LDS row,
    // build A = sum(x^2) replicating numpy pairwise_sum(64):
    // chunk c -> (i = c>>1, j = (c&1)*4+e); each r[j] sees i ascending.
    const float* xp = x + ((size_t)b * DIM) * HW + hw;
    float4* xrow = &xls[tid * ROWD];
    float r[8];
    #pragma unroll
    for (int c = 0; c < 16; ++c) {
        float v[4];
        #pragma unroll
        for (int e = 0; e < 4; ++e) v[e] = xp[(size_t)(4 * c + e) * HW];
        float4 ch;
        ch.x = v[0] + v[0]; ch.y = v[1] + v[1];     // exact doubling
        ch.z = v[2] + v[2]; ch.w = v[3] + v[3];
        xrow[c] = ch;                               // ds_write_b128, own row
        #pragma unroll
        for (int e = 0; e < 4; ++e) {
            const int j = (c & 1) * 4 + e;
            float pp = __fmul_rn(v[e], v[e]);
            if (c < 2) r[j] = pp;
            else       r[j] = __fadd_rn(r[j], pp);
        }
    }
    const float A = tree8(r[0], r[1], r[2], r[3], r[4], r[5], r[6], r[7]);

    // ---- argmin over codes, 4 codes per pass; coalesced float4 zero-fill.
    float best  = INFINITY;
    int   bestk = 0;
    const size_t T0 = ENC_OFF + (size_t)blockIdx.x * (TB * KCODES);  // tile base (dwords), T0%4==1
    float4* zs4 = reinterpret_cast<float4*>(out + T0 + 3);           // 16B-aligned
    const float4 zero4 = make_float4(0.0f, 0.0f, 0.0f, 0.0f);

    for (int k0 = 0; k0 < KCODES; k0 += 4) {
        float acc[4][8];
        const float* wp = w + (size_t)k0 * DIM;       // wave-uniform -> s_load path
        #pragma unroll
        for (int c = 0; c < 16; ++c) {
            float4 xc4 = xrow[c];                     // ds_read_b128, reused by 4 codes
            float xc[4] = {xc4.x, xc4.y, xc4.z, xc4.w};
            #pragma unroll
            for (int kk = 0; kk < 4; ++kk) {
                const float* wk = wp + kk * DIM + 4 * c;
                #pragma unroll
                for (int e = 0; e < 4; ++e) {
                    const int j = (c & 1) * 4 + e;
                    if (c < 2) acc[kk][j] = __fmul_rn(xc[e], wk[e]);   // == fmaf(a,b,0)
                    else       acc[kk][j] = __fmaf_rn(xc[e], wk[e], acc[kk][j]);
                }
            }
        }
        #pragma unroll
        for (int kk = 0; kk < 4; ++kk) {
            float dot  = tree8(acc[kk][0], acc[kk][1], acc[kk][2], acc[kk][3],
                               acc[kk][4], acc[kk][5], acc[kk][6], acc[kk][7]);
            float t    = __fadd_rn(A, ww[k0 + kk]);   // (||x||^2 + ||w_k||^2), ref order
            float dist = __fadd_rn(t, -dot);          // minus 2*x.w
            if (dist < best) { best = dist; bestk = k0 + kk; }
        }
        // coalesced zero-fill: 1 float4 per thread per iter, lanes contiguous
        const int m = (k0 >> 2) * TB + tid;           // [0, 16384)
        if (m < 16383) zs4[m] = zero4;                // m=16383 crosses tile edge
    }

    // edge dwords of this tile (not covered by the float4 sweep)
    if (tid < 3)   out[T0 + tid]   = 0.0f;            // d = 0,1,2
    if (tid == 3)  out[T0 + 65535] = 0.0f;            // d = 65535

    __syncthreads();   // vmcnt(0) drain of all zero stores; hcount init visible

    out[ENC_OFF + (size_t)n * KCODES + bestk] = 1.0f; // one-hot after zeros
    atomicAdd(&hcount[bestk], 1);

    // ---- quantized output (transposed back) + SSE partial
    const float4* wrow = reinterpret_cast<const float4*>(w + (size_t)bestk * DIM);
    float* qo = out + ((size_t)b * DIM) * HW + hw;
    float sse = 0.0f;
    #pragma unroll
    for (int c = 0; c < 16; ++c) {
        float4 q  = wrow[c];
        float4 xc = xrow[c];                          // 2x, so 0.5f* is exact
        qo[(size_t)(4 * c + 0) * HW] = q.x;
        qo[(size_t)(4 * c + 1) * HW] = q.y;
        qo[(size_t)(4 * c + 2) * HW] = q.z;
        qo[(size_t)(4 * c + 3) * HW] = q.w;
        float e0 = q.x - 0.5f * xc.x; sse = __fmaf_rn(e0, e0, sse);
        float e1 = q.y - 0.5f * xc.y; sse = __fmaf_rn(e1, e1, sse);
        float e2 = q.z - 0.5f * xc.z; sse = __fmaf_rn(e2, e2, sse);
        float e3 = q.w - 0.5f * xc.w; sse = __fmaf_rn(e3, e3, sse);
    }
    lred[tid] = sse;
    __syncthreads();

    // histogram drain (after barrier: all hcount atomics done)
    #pragma unroll
    for (int i = 0; i < 4; ++i) {
        int c0 = hcount[tid + i * TB];
        if (c0) atomicAdd(&counts[tid + i * TB], c0);
    }

    // block loss reduction
    for (int s = TB / 2; s > 0; s >>= 1) {
        if (tid < s) lred[tid] += lred[tid + s];
        __syncthreads();
    }
    if (tid == 0) atomicAdd(lossAcc, lred[0]);
}

// Finalize: loss scalar + perplexity from histogram.
extern "C" __global__ __launch_bounds__(512)
void vq_finalize(const int* __restrict__ counts, const float* __restrict__ lossAcc,
                 float* __restrict__ out)
{
    __shared__ double sred[KCODES];
    const int t = threadIdx.x;                 // 512 threads
    double p = (double)counts[t] * (1.0 / (double)NPOS);
    sred[t] = -p * log(p + 1e-10);
    __syncthreads();
    for (int s = KCODES / 2; s > 0; s >>= 1) {
        if (t < s) sred[t] += sred[t + s];
        __syncthreads();
    }
    if (t == 0) {
        out[PERP_OFF] = (float)exp(sred[0]);
        out[LOSS_OFF] = 1.25f * (lossAcc[0] / 8388608.0f);
    }
}

extern "C" void kernel_launch(void* const* d_in, const int* in_sizes, int n_in,
                              void* d_out, int out_size, void* d_ws, size_t ws_size,
                              hipStream_t stream)
{
    const float* x = (const float*)d_in[0];    // [32,64,64,64] fp32
    const float* w = (const float*)d_in[1];    // [512,64] fp32
    float* out = (float*)d_out;

    float* ww      = (float*)d_ws;                         // 512 floats
    int*   counts  = (int*)((char*)d_ws + 2048);           // 512 ints
    float* lossAcc = (float*)((char*)d_ws + 4096);         // 1 float

    vq_prep<<<1, 512, 0, stream>>>(w, ww, counts, lossAcc);
    vq_main<<<NPOS / TB, TB, 0, stream>>>(x, w, ww, out, counts, lossAcc);
    vq_finalize<<<1, 512, 0, stream>>>(counts, lossAcc, out);
}